// Round 1
// baseline (3204.864 us; speedup 1.0000x reference)
//
#include <hip/hip_runtime.h>
#include <hip/hip_bf16.h>
#include <stdint.h>

typedef unsigned short u16;
typedef __attribute__((ext_vector_type(4))) float floatx4;
typedef __attribute__((ext_vector_type(8))) short bf16x8;
typedef const __attribute__((address_space(1))) void gvoid;
typedef __attribute__((address_space(3))) void lvoid;

static constexpr int Mdim = 4096;   // B*S = 4*1024
static constexpr int Hdim = 5120;
static constexpr int Idim = 12288;
static constexpr float QINV = 1.0f / 127.0f;

// ---- int32 -> bf16 weight conversion (values in [-127,127] are exact in bf16)
__global__ void conv_i32_to_bf16(const int* __restrict__ in, u16* __restrict__ out) {
    int idx = (blockIdx.x * 256 + threadIdx.x) * 4;
    int4 v = *(const int4*)(in + idx);
    __hip_bfloat16 b0 = __float2bfloat16((float)v.x);
    __hip_bfloat16 b1 = __float2bfloat16((float)v.y);
    __hip_bfloat16 b2 = __float2bfloat16((float)v.z);
    __hip_bfloat16 b3 = __float2bfloat16((float)v.w);
    ushort4 o;
    o.x = *(u16*)&b0; o.y = *(u16*)&b1; o.z = *(u16*)&b2; o.w = *(u16*)&b3;
    *(ushort4*)(out + idx) = o;
}

// ---- f32 -> bf16 activation conversion
__global__ void conv_f32_to_bf16(const float* __restrict__ in, u16* __restrict__ out) {
    int idx = (blockIdx.x * 256 + threadIdx.x) * 4;
    float4 v = *(const float4*)(in + idx);
    __hip_bfloat16 b0 = __float2bfloat16(v.x);
    __hip_bfloat16 b1 = __float2bfloat16(v.y);
    __hip_bfloat16 b2 = __float2bfloat16(v.z);
    __hip_bfloat16 b3 = __float2bfloat16(v.w);
    ushort4 o;
    o.x = *(u16*)&b0; o.y = *(u16*)&b1; o.z = *(u16*)&b2; o.w = *(u16*)&b3;
    *(ushort4*)(out + idx) = o;
}

// ---- m97-style bf16 GEMM, C[m][n] = sum_k A[m,k]*W[n,k], fused epilogues.
// MODE 0: GateBuf = bf16(silu(acc*s))        (gate projection)
// MODE 1: GateBuf = bf16(GateBuf * acc*s)    (up projection, in-place gate*up)
// MODE 2: OutF    = acc*s                    (down projection, fp32 out)
template<int MODE>
__global__ __launch_bounds__(256)
void gemm_bt(const u16* __restrict__ A, const u16* __restrict__ Bw,
             const float* __restrict__ scale, u16* __restrict__ GateBuf,
             float* __restrict__ OutF, int N, int K)
{
    constexpr int BM = 128, BN = 128, BK = 64;
    __shared__ u16 As[BM * BK];   // 16 KB
    __shared__ u16 Bs[BN * BK];   // 16 KB
    const int tid  = threadIdx.x;
    const int lane = tid & 63;
    const int wave = tid >> 6;
    const int row0 = blockIdx.x * BM;
    const int col0 = blockIdx.y * BN;
    const int wm = (wave & 1) * 64;   // wave tile 64x64, 2x2 wave grid
    const int wn = (wave >> 1) * 64;
    const int lm = lane & 15;
    const int kg = (lane >> 4) * 8;   // contiguous-8 K chunk per lane group

    floatx4 acc[4][4];
    #pragma unroll
    for (int i = 0; i < 4; i++)
        #pragma unroll
        for (int j = 0; j < 4; j++)
            acc[i][j] = (floatx4){0.f, 0.f, 0.f, 0.f};

    const u16* Ablk = A  + (size_t)row0 * K;
    const u16* Bblk = Bw + (size_t)col0 * K;

    for (int kt = 0; kt < K; kt += BK) {
        __syncthreads();
        // stage 128x64 bf16 tiles: 1024 x 16B per tile, 4 insts/thread/tile.
        // LDS dest is wave-uniform base + lane*16 -> slot layout is contiguous.
        #pragma unroll
        for (int i = 0; i < 4; i++) {
            int slot = i * 256 + tid;     // 0..1023
            int r = slot >> 3;            // row in tile
            int c = (slot & 7) * 8;       // k elem offset
            __builtin_amdgcn_global_load_lds((gvoid*)(Ablk + (size_t)r * K + kt + c),
                                             (lvoid*)(As + slot * 8), 16, 0, 0);
            __builtin_amdgcn_global_load_lds((gvoid*)(Bblk + (size_t)r * K + kt + c),
                                             (lvoid*)(Bs + slot * 8), 16, 0, 0);
        }
        __syncthreads();
        #pragma unroll
        for (int kk = 0; kk < BK; kk += 32) {
            bf16x8 af[4], bfr[4];
            #pragma unroll
            for (int i = 0; i < 4; i++) {
                af[i]  = *(const bf16x8*)(As + (wm + i * 16 + lm) * BK + kk + kg);
                bfr[i] = *(const bf16x8*)(Bs + (wn + i * 16 + lm) * BK + kk + kg);
            }
            #pragma unroll
            for (int i = 0; i < 4; i++)
                #pragma unroll
                for (int j = 0; j < 4; j++)
                    acc[i][j] = __builtin_amdgcn_mfma_f32_16x16x32_bf16(af[i], bfr[j], acc[i][j], 0, 0, 0);
        }
    }

    // epilogue: C/D layout col=lane&15, row=(lane>>4)*4+reg   [m89-verified]
    const int ln = lane & 15;
    const int rq = (lane >> 4) * 4;
    #pragma unroll
    for (int j = 0; j < 4; j++) {
        const int col = col0 + wn + j * 16 + ln;
        const float s = scale[col] * QINV;
        #pragma unroll
        for (int i = 0; i < 4; i++) {
            const int rowb = row0 + wm + i * 16 + rq;
            #pragma unroll
            for (int r = 0; r < 4; r++) {
                const size_t idx = (size_t)(rowb + r) * N + col;
                float v = acc[i][j][r] * s;
                if (MODE == 0) {
                    float g = v / (1.0f + __expf(-v));   // silu
                    __hip_bfloat16 h = __float2bfloat16(g);
                    GateBuf[idx] = *(u16*)&h;
                } else if (MODE == 1) {
                    u16 gu = GateBuf[idx];
                    float g = __bfloat162float(*(__hip_bfloat16*)&gu);
                    __hip_bfloat16 h = __float2bfloat16(g * v);
                    GateBuf[idx] = *(u16*)&h;
                } else {
                    OutF[idx] = v;
                }
            }
        }
    }
}

extern "C" void kernel_launch(void* const* d_in, const int* in_sizes, int n_in,
                              void* d_out, int out_size, void* d_ws, size_t ws_size,
                              hipStream_t stream)
{
    const float* x  = (const float*)d_in[0];
    const int*   wg = (const int*)d_in[1];
    const float* sg = (const float*)d_in[2];
    const int*   wu = (const int*)d_in[3];
    const float* su = (const float*)d_in[4];
    const int*   wd = (const int*)d_in[5];
    const float* sd = (const float*)d_in[6];
    float* out = (float*)d_out;

    char* ws = (char*)d_ws;
    u16* xb   = (u16*)ws;                                        // 4096*5120 bf16   (42 MB)
    u16* wb   = (u16*)(ws + 41943040);                           // 62914560 bf16    (126 MB, reused 3x)
    u16* gate = (u16*)(ws + 41943040 + 125829120);               // 4096*12288 bf16  (100 MB, gate then h)

    // x: 20971520 elems / 1024 per block
    conv_f32_to_bf16<<<20480, 256, 0, stream>>>(x, xb);

    // gate = silu((x @ Wg^T) * sg/127)
    conv_i32_to_bf16<<<61440, 256, 0, stream>>>(wg, wb);
    gemm_bt<0><<<dim3(Mdim / 128, Idim / 128), 256, 0, stream>>>(xb, wb, sg, gate, nullptr, Idim, Hdim);

    // h = gate * ((x @ Wu^T) * su/127)   (in-place over gate)
    conv_i32_to_bf16<<<61440, 256, 0, stream>>>(wu, wb);
    gemm_bt<1><<<dim3(Mdim / 128, Idim / 128), 256, 0, stream>>>(xb, wb, su, gate, nullptr, Idim, Hdim);

    // out = (h @ Wd^T) * sd/127
    conv_i32_to_bf16<<<61440, 256, 0, stream>>>(wd, wb);
    gemm_bt<2><<<dim3(Mdim / 128, Hdim / 128), 256, 0, stream>>>(gate, wb, sd, nullptr, out, Hdim, Idim);
}

// Round 2
// 2926.386 us; speedup vs baseline: 1.0952x; 1.0952x over previous
//
#include <hip/hip_runtime.h>
#include <hip/hip_bf16.h>
#include <stdint.h>

typedef unsigned short u16;
typedef __attribute__((ext_vector_type(4))) float floatx4;
typedef __attribute__((ext_vector_type(8))) short bf16x8;
typedef const __attribute__((address_space(1))) void gvoid;
typedef __attribute__((address_space(3))) void lvoid;

static constexpr int Mdim = 4096;   // B*S = 4*1024
static constexpr int Hdim = 5120;
static constexpr int Idim = 12288;
static constexpr float QINV = 1.0f / 127.0f;

// ---- int32 -> bf16 weight conversion (values in [-127,127] are exact in bf16)
__global__ void conv_i32_to_bf16(const int* __restrict__ in, u16* __restrict__ out) {
    int idx = (blockIdx.x * 256 + threadIdx.x) * 4;
    int4 v = *(const int4*)(in + idx);
    __hip_bfloat16 b0 = __float2bfloat16((float)v.x);
    __hip_bfloat16 b1 = __float2bfloat16((float)v.y);
    __hip_bfloat16 b2 = __float2bfloat16((float)v.z);
    __hip_bfloat16 b3 = __float2bfloat16((float)v.w);
    ushort4 o;
    o.x = *(u16*)&b0; o.y = *(u16*)&b1; o.z = *(u16*)&b2; o.w = *(u16*)&b3;
    *(ushort4*)(out + idx) = o;
}

// ---- f32 -> bf16 activation conversion
__global__ void conv_f32_to_bf16(const float* __restrict__ in, u16* __restrict__ out) {
    int idx = (blockIdx.x * 256 + threadIdx.x) * 4;
    float4 v = *(const float4*)(in + idx);
    __hip_bfloat16 b0 = __float2bfloat16(v.x);
    __hip_bfloat16 b1 = __float2bfloat16(v.y);
    __hip_bfloat16 b2 = __float2bfloat16(v.z);
    __hip_bfloat16 b3 = __float2bfloat16(v.w);
    ushort4 o;
    o.x = *(u16*)&b0; o.y = *(u16*)&b1; o.z = *(u16*)&b2; o.w = *(u16*)&b3;
    *(ushort4*)(out + idx) = o;
}

// ---- m97-style bf16 GEMM, C[m][n] = sum_k A[m,k]*W[n,k], fused epilogues.
// LDS tiles use an XOR swizzle on the 16B units within each 128B row:
//   unit u of row r holds global chunk (u ^ (r&7)).
// Row stride is 128B = 32 banks, so WITHOUT the swizzle all 16 consecutive-row
// lanes of a ds_read_b128 hit the same 4 banks (16-way conflict, ~5.7x; R1
// measured SQ_LDS_BANK_CONFLICT=1.9e8). With it, lanes spread across all 8
// bank groups (2-way = free per m136). global_load_lds dest stays contiguous.
// MODE 0: GateBuf = bf16(silu(acc*s))        (gate projection)
// MODE 1: GateBuf = bf16(GateBuf * acc*s)    (up projection, in-place gate*up)
// MODE 2: OutF    = acc*s                    (down projection, fp32 out)
template<int MODE>
__global__ __launch_bounds__(256)
void gemm_bt(const u16* __restrict__ A, const u16* __restrict__ Bw,
             const float* __restrict__ scale, u16* __restrict__ GateBuf,
             float* __restrict__ OutF, int N, int K)
{
    constexpr int BM = 128, BN = 128, BK = 64;
    __shared__ u16 As[BM * BK];   // 16 KB
    __shared__ u16 Bs[BN * BK];   // 16 KB
    const int tid  = threadIdx.x;
    const int lane = tid & 63;
    const int wave = tid >> 6;
    const int row0 = blockIdx.x * BM;
    const int col0 = blockIdx.y * BN;
    const int wm = (wave & 1) * 64;   // wave tile 64x64, 2x2 wave grid
    const int wn = (wave >> 1) * 64;
    const int lm = lane & 15;
    const int lg = lane >> 4;         // 0..3 -> which 8-elem K chunk

    floatx4 acc[4][4];
    #pragma unroll
    for (int i = 0; i < 4; i++)
        #pragma unroll
        for (int j = 0; j < 4; j++)
            acc[i][j] = (floatx4){0.f, 0.f, 0.f, 0.f};

    const u16* Ablk = A  + (size_t)row0 * K;
    const u16* Bblk = Bw + (size_t)col0 * K;

    for (int kt = 0; kt < K; kt += BK) {
        __syncthreads();
        // stage 128x64 bf16 tiles: 1024 x 16B per tile, 4 insts/thread/tile.
        // LDS dest = wave-uniform base + lane*16 (contiguous); the XOR swizzle
        // is applied on the SOURCE column instead.
        #pragma unroll
        for (int i = 0; i < 4; i++) {
            int slot = i * 256 + tid;          // 0..1023
            int r = slot >> 3;                 // row in tile
            int u = slot & 7;                  // 16B unit within row
            int c = (u ^ (r & 7)) * 8;         // swizzled k elem offset
            __builtin_amdgcn_global_load_lds((gvoid*)(Ablk + (size_t)r * K + kt + c),
                                             (lvoid*)(As + slot * 8), 16, 0, 0);
            __builtin_amdgcn_global_load_lds((gvoid*)(Bblk + (size_t)r * K + kt + c),
                                             (lvoid*)(Bs + slot * 8), 16, 0, 0);
        }
        __syncthreads();
        #pragma unroll
        for (int kk = 0; kk < BK; kk += 32) {
            bf16x8 af[4], bfr[4];
            #pragma unroll
            for (int i = 0; i < 4; i++) {
                const int rA = wm + i * 16 + lm;
                const int rB = wn + i * 16 + lm;
                const int uu = ((kk >> 3) + lg);              // c8 unit index
                af[i]  = *(const bf16x8*)(As + rA * BK + ((uu ^ (lm & 7)) << 3));
                bfr[i] = *(const bf16x8*)(Bs + rB * BK + ((uu ^ (lm & 7)) << 3));
            }
            #pragma unroll
            for (int i = 0; i < 4; i++)
                #pragma unroll
                for (int j = 0; j < 4; j++)
                    acc[i][j] = __builtin_amdgcn_mfma_f32_16x16x32_bf16(af[i], bfr[j], acc[i][j], 0, 0, 0);
        }
    }

    // epilogue: C/D layout col=lane&15, row=(lane>>4)*4+reg   [m89-verified]
    const int ln = lane & 15;
    const int rq = (lane >> 4) * 4;
    #pragma unroll
    for (int j = 0; j < 4; j++) {
        const int col = col0 + wn + j * 16 + ln;
        const float s = scale[col] * QINV;
        #pragma unroll
        for (int i = 0; i < 4; i++) {
            const int rowb = row0 + wm + i * 16 + rq;
            #pragma unroll
            for (int r = 0; r < 4; r++) {
                const size_t idx = (size_t)(rowb + r) * N + col;
                float v = acc[i][j][r] * s;
                if (MODE == 0) {
                    float g = v / (1.0f + __expf(-v));   // silu
                    __hip_bfloat16 h = __float2bfloat16(g);
                    GateBuf[idx] = *(u16*)&h;
                } else if (MODE == 1) {
                    u16 gu = GateBuf[idx];
                    float g = __bfloat162float(*(__hip_bfloat16*)&gu);
                    __hip_bfloat16 h = __float2bfloat16(g * v);
                    GateBuf[idx] = *(u16*)&h;
                } else {
                    OutF[idx] = v;
                }
            }
        }
    }
}

extern "C" void kernel_launch(void* const* d_in, const int* in_sizes, int n_in,
                              void* d_out, int out_size, void* d_ws, size_t ws_size,
                              hipStream_t stream)
{
    const float* x  = (const float*)d_in[0];
    const int*   wg = (const int*)d_in[1];
    const float* sg = (const float*)d_in[2];
    const int*   wu = (const int*)d_in[3];
    const float* su = (const float*)d_in[4];
    const int*   wd = (const int*)d_in[5];
    const float* sd = (const float*)d_in[6];
    float* out = (float*)d_out;

    char* ws = (char*)d_ws;
    u16* xb   = (u16*)ws;                                        // 4096*5120 bf16   (42 MB)
    u16* wb   = (u16*)(ws + 41943040);                           // 62914560 bf16    (126 MB, reused 3x)
    u16* gate = (u16*)(ws + 41943040 + 125829120);               // 4096*12288 bf16  (100 MB, gate then h)

    // x: 20971520 elems / 1024 per block
    conv_f32_to_bf16<<<20480, 256, 0, stream>>>(x, xb);

    // gate = silu((x @ Wg^T) * sg/127)
    conv_i32_to_bf16<<<61440, 256, 0, stream>>>(wg, wb);
    gemm_bt<0><<<dim3(Mdim / 128, Idim / 128), 256, 0, stream>>>(xb, wb, sg, gate, nullptr, Idim, Hdim);

    // h = gate * ((x @ Wu^T) * su/127)   (in-place over gate)
    conv_i32_to_bf16<<<61440, 256, 0, stream>>>(wu, wb);
    gemm_bt<1><<<dim3(Mdim / 128, Idim / 128), 256, 0, stream>>>(xb, wb, su, gate, nullptr, Idim, Hdim);

    // out = (h @ Wd^T) * sd/127
    conv_i32_to_bf16<<<61440, 256, 0, stream>>>(wd, wb);
    gemm_bt<2><<<dim3(Mdim / 128, Hdim / 128), 256, 0, stream>>>(gate, wb, sd, nullptr, out, Hdim, Idim);
}